// Round 2
// baseline (119.102 us; speedup 1.0000x reference)
//
#include <hip/hip_runtime.h>

namespace {
constexpr int   kB     = 256;
constexpr int   kN     = 50;
constexpr int   kD     = 128;
constexpr int   kRP    = 132;   // padded LDS row stride in floats ((lane+d4)%32 quad-bank rotation)
constexpr int   kRows  = 64;    // staged rows (50 real + zero padding)
constexpr int   kNG    = 13;    // 4-row groups (last group has rows 48,49 real; 50,51 padded)
constexpr float kNeg   = -9.0e15f;
constexpr float kSlope = 0.2f;
}

__global__ __launch_bounds__(512, 4)
void gat_fused2_kernel(const float* __restrict__ hidden,
                       const int*   __restrict__ adj,
                       const float* __restrict__ a0,
                       const float* __restrict__ a1,
                       const float* __restrict__ a2,
                       const float* __restrict__ a3,
                       float* __restrict__ out)
{
    __shared__ float hsh[kRows * kRP];   // 64 x 128 staged hidden rows (rows >=50 zeroed)
    __shared__ float wsh[4 * kRP];       // 4 relation vectors
    __shared__ float ash[8][4][64];      // per-wave attention rows (4 rows in flight)

    const int b    = blockIdx.x >> 1;
    const int half = blockIdx.x & 1;
    const int tid  = threadIdx.x;
    const int lane = tid & 63;
    const int wid  = tid >> 6;

    // ---- stage hidden[b] into LDS (float4, coalesced); zero pad rows ----
    const float4* hg = reinterpret_cast<const float4*>(hidden + (size_t)b * (kN * kD));
    for (int idx = tid; idx < kRows * (kD / 4); idx += 512) {
        const int j  = idx >> 5;     // row (32 float4 per row)
        const int d4 = idx & 31;
        float4 v = make_float4(0.f, 0.f, 0.f, 0.f);
        if (idx < kN * (kD / 4)) v = hg[idx];
        *reinterpret_cast<float4*>(&hsh[j * kRP + d4 * 4]) = v;
    }
    if (tid < kD) {
        wsh[0 * kRP + tid] = a0[tid];
        wsh[1 * kRP + tid] = a1[tid];
        wsh[2 * kRP + tid] = a2[tid];
        wsh[3 * kRP + tid] = a3[tid];
    }
    __syncthreads();

    // each wave owns one 4-row group; blocks split groups by parity
    const int g = 2 * wid + half;
    if (g >= kNG) return;

    const int*  adjb = adj + (size_t)b * (kN * kN);
    float*      outb = out + (size_t)b * (kN * kD);
    const int   i0   = 4 * g;

    // ---- scores: all-4-relation accumulation with broadcast w reads ----
    float acc[4][4];
    #pragma unroll
    for (int r = 0; r < 4; ++r)
        #pragma unroll
        for (int k = 0; k < 4; ++k) acc[r][k] = 0.f;

    const float4* hj4 = reinterpret_cast<const float4*>(&hsh[lane * kRP]);        // per-lane
    const float4* hr0 = reinterpret_cast<const float4*>(&hsh[(i0 + 0) * kRP]);    // broadcast
    const float4* hr1 = reinterpret_cast<const float4*>(&hsh[(i0 + 1) * kRP]);
    const float4* hr2 = reinterpret_cast<const float4*>(&hsh[(i0 + 2) * kRP]);
    const float4* hr3 = reinterpret_cast<const float4*>(&hsh[(i0 + 3) * kRP]);
    const float4* w40 = reinterpret_cast<const float4*>(&wsh[0 * kRP]);           // broadcast
    const float4* w41 = reinterpret_cast<const float4*>(&wsh[1 * kRP]);
    const float4* w42 = reinterpret_cast<const float4*>(&wsh[2 * kRP]);
    const float4* w43 = reinterpret_cast<const float4*>(&wsh[3 * kRP]);

    #pragma unroll 4
    for (int d4 = 0; d4 < kD / 4; ++d4) {
        const float4 hj = hj4[d4];
        const float4 h0 = hr0[d4];
        const float4 h1 = hr1[d4];
        const float4 h2 = hr2[d4];
        const float4 h3 = hr3[d4];
        const float4 w0 = w40[d4];
        const float4 w1 = w41[d4];
        const float4 w2 = w42[d4];
        const float4 w3 = w43[d4];
        #define GAT_COMP(c)                                                  \
        {                                                                    \
            const float t0 = h0.c * hj.c;                                    \
            const float t1 = h1.c * hj.c;                                    \
            const float t2 = h2.c * hj.c;                                    \
            const float t3 = h3.c * hj.c;                                    \
            acc[0][0] += t0 * w0.c; acc[0][1] += t0 * w1.c;                  \
            acc[0][2] += t0 * w2.c; acc[0][3] += t0 * w3.c;                  \
            acc[1][0] += t1 * w0.c; acc[1][1] += t1 * w1.c;                  \
            acc[1][2] += t1 * w2.c; acc[1][3] += t1 * w3.c;                  \
            acc[2][0] += t2 * w0.c; acc[2][1] += t2 * w1.c;                  \
            acc[2][2] += t2 * w2.c; acc[2][3] += t2 * w3.c;                  \
            acc[3][0] += t3 * w0.c; acc[3][1] += t3 * w1.c;                  \
            acc[3][2] += t3 * w2.c; acc[3][3] += t3 * w3.c;                  \
        }
        GAT_COMP(x) GAT_COMP(y) GAT_COMP(z) GAT_COMP(w)
        #undef GAT_COMP
    }

    // ---- select by edge type, leaky-relu, mask ----
    const bool jv = (lane < kN);
    float s[4];
    #pragma unroll
    for (int r = 0; r < 4; ++r) {
        const int ii = i0 + r;
        int kv = 0;
        if (jv && ii < kN) kv = adjb[ii * kN + lane];
        float sel = (kv == 1) ? acc[r][0]
                  : (kv == 2) ? acc[r][1]
                  : (kv == 3) ? acc[r][2]
                  : (kv == 4) ? acc[r][3] : kNeg;
        const float l = (sel > 0.f) ? sel : kSlope * sel;
        s[r] = (kv >= 1 && kv <= 4) ? l : kNeg;
    }

    // ---- wave-parallel softmax over j for 4 rows ----
    float m0 = s[0], m1 = s[1], m2 = s[2], m3 = s[3];
    #pragma unroll
    for (int o = 32; o; o >>= 1) {
        m0 = fmaxf(m0, __shfl_xor(m0, o));
        m1 = fmaxf(m1, __shfl_xor(m1, o));
        m2 = fmaxf(m2, __shfl_xor(m2, o));
        m3 = fmaxf(m3, __shfl_xor(m3, o));
    }
    const float e0 = jv ? __expf(s[0] - m0) : 0.f;  // all-masked row -> uniform, matches ref
    const float e1 = jv ? __expf(s[1] - m1) : 0.f;
    const float e2 = jv ? __expf(s[2] - m2) : 0.f;
    const float e3 = jv ? __expf(s[3] - m3) : 0.f;
    float t0 = e0, t1 = e1, t2 = e2, t3 = e3;
    #pragma unroll
    for (int o = 32; o; o >>= 1) {
        t0 += __shfl_xor(t0, o);
        t1 += __shfl_xor(t1, o);
        t2 += __shfl_xor(t2, o);
        t3 += __shfl_xor(t3, o);
    }
    ash[wid][0][lane] = e0 / t0;
    ash[wid][1][lane] = e1 / t1;
    ash[wid][2][lane] = e2 / t2;
    ash[wid][3][lane] = e3 / t3;

    // ---- PV: out[i,:] = sum_j attn[i,j] * h[j,:]; lane owns 2 d's ----
    const int dbase = 2 * lane;
    float o00 = 0.f, o01 = 0.f, o10 = 0.f, o11 = 0.f;
    float o20 = 0.f, o21 = 0.f, o30 = 0.f, o31 = 0.f;
    #pragma unroll 5
    for (int jj = 0; jj < kN; ++jj) {
        const float2 h2 = *reinterpret_cast<const float2*>(&hsh[jj * kRP + dbase]);
        const float av0 = ash[wid][0][jj];
        const float av1 = ash[wid][1][jj];
        const float av2 = ash[wid][2][jj];
        const float av3 = ash[wid][3][jj];
        o00 += av0 * h2.x;  o01 += av0 * h2.y;
        o10 += av1 * h2.x;  o11 += av1 * h2.y;
        o20 += av2 * h2.x;  o21 += av2 * h2.y;
        o30 += av3 * h2.x;  o31 += av3 * h2.y;
    }
    if (i0 + 0 < kN) { float2 r{o00, o01}; *reinterpret_cast<float2*>(&outb[(i0 + 0) * kD + dbase]) = r; }
    if (i0 + 1 < kN) { float2 r{o10, o11}; *reinterpret_cast<float2*>(&outb[(i0 + 1) * kD + dbase]) = r; }
    if (i0 + 2 < kN) { float2 r{o20, o21}; *reinterpret_cast<float2*>(&outb[(i0 + 2) * kD + dbase]) = r; }
    if (i0 + 3 < kN) { float2 r{o30, o31}; *reinterpret_cast<float2*>(&outb[(i0 + 3) * kD + dbase]) = r; }
}

extern "C" void kernel_launch(void* const* d_in, const int* in_sizes, int n_in,
                              void* d_out, int out_size, void* d_ws, size_t ws_size,
                              hipStream_t stream) {
    const float* hidden = reinterpret_cast<const float*>(d_in[0]);
    const int*   adjp   = reinterpret_cast<const int*>(d_in[1]);
    const float* a0     = reinterpret_cast<const float*>(d_in[2]);
    const float* a1     = reinterpret_cast<const float*>(d_in[3]);
    const float* a2     = reinterpret_cast<const float*>(d_in[4]);
    const float* a3     = reinterpret_cast<const float*>(d_in[5]);
    float*       outp   = reinterpret_cast<float*>(d_out);

    gat_fused2_kernel<<<dim3(kB * 2), dim3(512), 0, stream>>>(
        hidden, adjp, a0, a1, a2, a3, outp);
}

// Round 3
// 33.896 us; speedup vs baseline: 3.5138x; 3.5138x over previous
//
#include <hip/hip_runtime.h>

namespace {
constexpr int   kB     = 256;
constexpr int   kN     = 50;
constexpr int   kD     = 128;
constexpr int   kRP    = 132;   // LDS row stride in floats: (4*(lane+d4))%32 quad rotation -> balanced banks
constexpr int   kRows  = 64;    // staged rows (50 real + 14 zeroed)
constexpr int   kNG    = 13;    // 4-row groups (rows 48..51; 50,51 are padding)
constexpr float kNeg   = -9.0e15f;
constexpr float kSlope = 0.2f;
}

__global__ __launch_bounds__(256)
void gat_fused3_kernel(const float* __restrict__ hidden,
                       const int*   __restrict__ adj,
                       const float* __restrict__ a0,
                       const float* __restrict__ a1,
                       const float* __restrict__ a2,
                       const float* __restrict__ a3,
                       float* __restrict__ out)
{
    __shared__ float hsh[kRows * kRP];   // h_j rows for per-lane access (33.8 KB)

    const int b       = blockIdx.x >> 2;      // 4 blocks per batch
    const int quarter = blockIdx.x & 3;
    const int tid     = threadIdx.x;
    const int lane    = tid & 63;
    const int wid     = tid >> 6;

    const float* __restrict__ hb = hidden + (size_t)b * (kN * kD);

    // ---- stage hidden[b] into LDS (float4, coalesced); zero the pad rows ----
    const float4* hg = reinterpret_cast<const float4*>(hb);
    for (int idx = tid; idx < kRows * (kD / 4); idx += 256) {
        const int j  = idx >> 5;
        const int d4 = idx & 31;
        float4 v = make_float4(0.f, 0.f, 0.f, 0.f);
        if (idx < kN * (kD / 4)) v = hg[idx];
        *reinterpret_cast<float4*>(&hsh[j * kRP + d4 * 4]) = v;
    }
    __syncthreads();

    // each wave owns one 4-row group; 4 blocks x 4 waves = 16 slots for 13 groups
    const int g = 4 * wid + quarter;
    if (g >= kNG) return;
    const int gu = __builtin_amdgcn_readfirstlane(g);   // force wave-uniform (SGPR)
    const int i0 = 4 * gu;

    const int*  adjb = adj + (size_t)b * (kN * kN);
    float*      outb = out + (size_t)b * (kN * kD);

    // wave-uniform row pointers -> scalar loads (clamp padded rows; results discarded)
    const float* __restrict__ hr0 = hb + (size_t)((i0 + 0 < kN) ? (i0 + 0) : (kN - 1)) * kD;
    const float* __restrict__ hr1 = hb + (size_t)((i0 + 1 < kN) ? (i0 + 1) : (kN - 1)) * kD;
    const float* __restrict__ hr2 = hb + (size_t)((i0 + 2 < kN) ? (i0 + 2) : (kN - 1)) * kD;
    const float* __restrict__ hr3 = hb + (size_t)((i0 + 3 < kN) ? (i0 + 3) : (kN - 1)) * kD;

    // ---- scores: t = h_i*h_j shared across the 4 relation accumulators;
    //      all broadcast operands come in through the scalar path ----
    float acc[4][4];
    #pragma unroll
    for (int r = 0; r < 4; ++r)
        #pragma unroll
        for (int k = 0; k < 4; ++k) acc[r][k] = 0.f;

    const float4* hj4 = reinterpret_cast<const float4*>(&hsh[lane * kRP]);  // per-lane LDS

    #pragma unroll 2
    for (int d4 = 0; d4 < kD / 4; ++d4) {
        const float4 hj = hj4[d4];                                          // ds_read_b128
        const float4 h0 = *reinterpret_cast<const float4*>(hr0 + 4 * d4);   // uniform -> s_load
        const float4 h1 = *reinterpret_cast<const float4*>(hr1 + 4 * d4);
        const float4 h2 = *reinterpret_cast<const float4*>(hr2 + 4 * d4);
        const float4 h3 = *reinterpret_cast<const float4*>(hr3 + 4 * d4);
        const float4 w0 = *reinterpret_cast<const float4*>(a0 + 4 * d4);
        const float4 w1 = *reinterpret_cast<const float4*>(a1 + 4 * d4);
        const float4 w2 = *reinterpret_cast<const float4*>(a2 + 4 * d4);
        const float4 w3 = *reinterpret_cast<const float4*>(a3 + 4 * d4);
        #define GAT_COMP(c)                                                  \
        {                                                                    \
            const float t0 = h0.c * hj.c;                                    \
            const float t1 = h1.c * hj.c;                                    \
            const float t2 = h2.c * hj.c;                                    \
            const float t3 = h3.c * hj.c;                                    \
            acc[0][0] += t0 * w0.c; acc[0][1] += t0 * w1.c;                  \
            acc[0][2] += t0 * w2.c; acc[0][3] += t0 * w3.c;                  \
            acc[1][0] += t1 * w0.c; acc[1][1] += t1 * w1.c;                  \
            acc[1][2] += t1 * w2.c; acc[1][3] += t1 * w3.c;                  \
            acc[2][0] += t2 * w0.c; acc[2][1] += t2 * w1.c;                  \
            acc[2][2] += t2 * w2.c; acc[2][3] += t2 * w3.c;                  \
            acc[3][0] += t3 * w0.c; acc[3][1] += t3 * w1.c;                  \
            acc[3][2] += t3 * w2.c; acc[3][3] += t3 * w3.c;                  \
        }
        GAT_COMP(x) GAT_COMP(y) GAT_COMP(z) GAT_COMP(w)
        #undef GAT_COMP
    }

    // ---- select by edge type, leaky-relu, mask ----
    const bool jv = (lane < kN);
    float s[4];
    #pragma unroll
    for (int r = 0; r < 4; ++r) {
        const int ii = i0 + r;
        int kv = 0;
        if (jv && ii < kN) kv = adjb[ii * kN + lane];
        float sel = (kv == 1) ? acc[r][0]
                  : (kv == 2) ? acc[r][1]
                  : (kv == 3) ? acc[r][2]
                  : (kv == 4) ? acc[r][3] : kNeg;
        const float l = (sel > 0.f) ? sel : kSlope * sel;
        s[r] = (kv >= 1 && kv <= 4) ? l : kNeg;
    }

    // ---- wave-parallel softmax over j for 4 rows ----
    float m0 = s[0], m1 = s[1], m2 = s[2], m3 = s[3];
    #pragma unroll
    for (int o = 32; o; o >>= 1) {
        m0 = fmaxf(m0, __shfl_xor(m0, o));
        m1 = fmaxf(m1, __shfl_xor(m1, o));
        m2 = fmaxf(m2, __shfl_xor(m2, o));
        m3 = fmaxf(m3, __shfl_xor(m3, o));
    }
    const float e0 = jv ? __expf(s[0] - m0) : 0.f;  // fully-masked row -> uniform, matches ref
    const float e1 = jv ? __expf(s[1] - m1) : 0.f;
    const float e2 = jv ? __expf(s[2] - m2) : 0.f;
    const float e3 = jv ? __expf(s[3] - m3) : 0.f;
    float t0 = e0, t1 = e1, t2 = e2, t3 = e3;
    #pragma unroll
    for (int o = 32; o; o >>= 1) {
        t0 += __shfl_xor(t0, o);
        t1 += __shfl_xor(t1, o);
        t2 += __shfl_xor(t2, o);
        t3 += __shfl_xor(t3, o);
    }
    const float at0 = e0 / t0;
    const float at1 = e1 / t1;
    const float at2 = e2 / t2;
    const float at3 = e3 / t3;

    // ---- PV: out[i,:] = sum_j attn[i,j]*h[j,:]; attn broadcast via v_readlane (SGPR) ----
    const int dbase = 2 * lane;
    float o00 = 0.f, o01 = 0.f, o10 = 0.f, o11 = 0.f;
    float o20 = 0.f, o21 = 0.f, o30 = 0.f, o31 = 0.f;
    #pragma unroll
    for (int jj = 0; jj < kN; ++jj) {
        const float2 h2 = *reinterpret_cast<const float2*>(&hsh[jj * kRP + dbase]);
        const float av0 = __uint_as_float(__builtin_amdgcn_readlane(__float_as_uint(at0), jj));
        const float av1 = __uint_as_float(__builtin_amdgcn_readlane(__float_as_uint(at1), jj));
        const float av2 = __uint_as_float(__builtin_amdgcn_readlane(__float_as_uint(at2), jj));
        const float av3 = __uint_as_float(__builtin_amdgcn_readlane(__float_as_uint(at3), jj));
        o00 += av0 * h2.x;  o01 += av0 * h2.y;
        o10 += av1 * h2.x;  o11 += av1 * h2.y;
        o20 += av2 * h2.x;  o21 += av2 * h2.y;
        o30 += av3 * h2.x;  o31 += av3 * h2.y;
    }
    if (i0 + 0 < kN) { float2 r{o00, o01}; *reinterpret_cast<float2*>(&outb[(i0 + 0) * kD + dbase]) = r; }
    if (i0 + 1 < kN) { float2 r{o10, o11}; *reinterpret_cast<float2*>(&outb[(i0 + 1) * kD + dbase]) = r; }
    if (i0 + 2 < kN) { float2 r{o20, o21}; *reinterpret_cast<float2*>(&outb[(i0 + 2) * kD + dbase]) = r; }
    if (i0 + 3 < kN) { float2 r{o30, o31}; *reinterpret_cast<float2*>(&outb[(i0 + 3) * kD + dbase]) = r; }
}

extern "C" void kernel_launch(void* const* d_in, const int* in_sizes, int n_in,
                              void* d_out, int out_size, void* d_ws, size_t ws_size,
                              hipStream_t stream) {
    const float* hidden = reinterpret_cast<const float*>(d_in[0]);
    const int*   adjp   = reinterpret_cast<const int*>(d_in[1]);
    const float* a0     = reinterpret_cast<const float*>(d_in[2]);
    const float* a1     = reinterpret_cast<const float*>(d_in[3]);
    const float* a2     = reinterpret_cast<const float*>(d_in[4]);
    const float* a3     = reinterpret_cast<const float*>(d_in[5]);
    float*       outp   = reinterpret_cast<float*>(d_out);

    gat_fused3_kernel<<<dim3(kB * 4), dim3(256), 0, stream>>>(
        hidden, adjp, a0, a1, a2, a3, outp);
}

// Round 4
// 27.931 us; speedup vs baseline: 4.2642x; 1.2136x over previous
//
#include <hip/hip_runtime.h>

namespace {
constexpr int   kB     = 256;
constexpr int   kN     = 50;
constexpr int   kD     = 128;
constexpr int   kRP    = 132;   // LDS row stride (floats); consecutive lanes -> distinct bank quads
constexpr int   kRows  = 64;    // staged rows (50 real + 14 zeroed)
constexpr int   kNG    = 13;    // 4-row groups
constexpr float kNeg   = -9.0e15f;
constexpr float kSlope = 0.2f;
}

__global__ __launch_bounds__(512)
void gat_fused4_kernel(const float* __restrict__ hidden,
                       const int*   __restrict__ adj,
                       const float* __restrict__ a0,
                       const float* __restrict__ a1,
                       const float* __restrict__ a2,
                       const float* __restrict__ a3,
                       float* __restrict__ out)
{
    __shared__ float hsh[kRows * kRP];    // 33.8 KB: h_j rows (per-lane + broadcast reads)
    __shared__ float wsh[4 * kRP];        //  2.1 KB: relation vectors (broadcast reads)
    __shared__ float ash[8][64][4];       //  8.0 KB: per-wave attn, transposed for b128 broadcast

    const int b    = blockIdx.x >> 1;     // 2 blocks per batch
    const int half = blockIdx.x & 1;
    const int tid  = threadIdx.x;
    const int lane = tid & 63;
    const int wid  = tid >> 6;

    const float* __restrict__ hb = hidden + (size_t)b * (kN * kD);

    // ---- stage hidden[b] + relation vectors into LDS (float4, coalesced) ----
    const float4* hg = reinterpret_cast<const float4*>(hb);
    for (int idx = tid; idx < kRows * (kD / 4); idx += 512) {
        const int j  = idx >> 5;
        const int d4 = idx & 31;
        float4 v = make_float4(0.f, 0.f, 0.f, 0.f);
        if (idx < kN * (kD / 4)) v = hg[idx];
        *reinterpret_cast<float4*>(&hsh[j * kRP + d4 * 4]) = v;
    }
    if (tid < kD) {
        wsh[0 * kRP + tid] = a0[tid];
        wsh[1 * kRP + tid] = a1[tid];
        wsh[2 * kRP + tid] = a2[tid];
        wsh[3 * kRP + tid] = a3[tid];
    }
    __syncthreads();

    // wave -> one 4-row group; even groups on half 0, odd on half 1
    const int g = 2 * wid + half;
    if (g >= kNG) return;
    const int i0 = 4 * g;

    const int*  adjb = adj + (size_t)b * (kN * kN);
    float*      outb = out + (size_t)b * (kN * kD);

    // ---- scores: per-lane hj (ds_read_b128) + broadcast h_i / w (uniform ds) ----
    float acc[4][4];
    #pragma unroll
    for (int r = 0; r < 4; ++r)
        #pragma unroll
        for (int k = 0; k < 4; ++k) acc[r][k] = 0.f;

    const float4* hj4 = reinterpret_cast<const float4*>(&hsh[lane * kRP]);
    const float4* hr0 = reinterpret_cast<const float4*>(&hsh[(i0 + 0) * kRP]);
    const float4* hr1 = reinterpret_cast<const float4*>(&hsh[(i0 + 1) * kRP]);
    const float4* hr2 = reinterpret_cast<const float4*>(&hsh[(i0 + 2) * kRP]);
    const float4* hr3 = reinterpret_cast<const float4*>(&hsh[(i0 + 3) * kRP]);
    const float4* w40 = reinterpret_cast<const float4*>(&wsh[0 * kRP]);
    const float4* w41 = reinterpret_cast<const float4*>(&wsh[1 * kRP]);
    const float4* w42 = reinterpret_cast<const float4*>(&wsh[2 * kRP]);
    const float4* w43 = reinterpret_cast<const float4*>(&wsh[3 * kRP]);

    #pragma unroll 2
    for (int d4 = 0; d4 < kD / 4; ++d4) {
        const float4 hj = hj4[d4];     // per-lane, conflict-free
        const float4 h0 = hr0[d4];     // uniform -> broadcast
        const float4 h1 = hr1[d4];
        const float4 h2 = hr2[d4];
        const float4 h3 = hr3[d4];
        const float4 w0 = w40[d4];
        const float4 w1 = w41[d4];
        const float4 w2 = w42[d4];
        const float4 w3 = w43[d4];
        #define GAT_COMP(c)                                                  \
        {                                                                    \
            const float t0 = h0.c * hj.c;                                    \
            const float t1 = h1.c * hj.c;                                    \
            const float t2 = h2.c * hj.c;                                    \
            const float t3 = h3.c * hj.c;                                    \
            acc[0][0] += t0 * w0.c; acc[0][1] += t0 * w1.c;                  \
            acc[0][2] += t0 * w2.c; acc[0][3] += t0 * w3.c;                  \
            acc[1][0] += t1 * w0.c; acc[1][1] += t1 * w1.c;                  \
            acc[1][2] += t1 * w2.c; acc[1][3] += t1 * w3.c;                  \
            acc[2][0] += t2 * w0.c; acc[2][1] += t2 * w1.c;                  \
            acc[2][2] += t2 * w2.c; acc[2][3] += t2 * w3.c;                  \
            acc[3][0] += t3 * w0.c; acc[3][1] += t3 * w1.c;                  \
            acc[3][2] += t3 * w2.c; acc[3][3] += t3 * w3.c;                  \
        }
        GAT_COMP(x) GAT_COMP(y) GAT_COMP(z) GAT_COMP(w)
        #undef GAT_COMP
    }

    // ---- select by edge type, leaky-relu, mask ----
    const bool jv = (lane < kN);
    float s[4];
    #pragma unroll
    for (int r = 0; r < 4; ++r) {
        const int ii = i0 + r;
        int kv = 0;
        if (jv && ii < kN) kv = adjb[ii * kN + lane];
        float sel = (kv == 1) ? acc[r][0]
                  : (kv == 2) ? acc[r][1]
                  : (kv == 3) ? acc[r][2]
                  : (kv == 4) ? acc[r][3] : kNeg;
        const float l = (sel > 0.f) ? sel : kSlope * sel;
        s[r] = (kv >= 1 && kv <= 4) ? l : kNeg;
    }

    // ---- wave-parallel softmax over j for 4 rows ----
    float m0 = s[0], m1 = s[1], m2 = s[2], m3 = s[3];
    #pragma unroll
    for (int o = 32; o; o >>= 1) {
        m0 = fmaxf(m0, __shfl_xor(m0, o));
        m1 = fmaxf(m1, __shfl_xor(m1, o));
        m2 = fmaxf(m2, __shfl_xor(m2, o));
        m3 = fmaxf(m3, __shfl_xor(m3, o));
    }
    const float e0 = jv ? __expf(s[0] - m0) : 0.f;  // fully-masked row -> uniform, matches ref
    const float e1 = jv ? __expf(s[1] - m1) : 0.f;
    const float e2 = jv ? __expf(s[2] - m2) : 0.f;
    const float e3 = jv ? __expf(s[3] - m3) : 0.f;
    float t0 = e0, t1 = e1, t2 = e2, t3 = e3;
    #pragma unroll
    for (int o = 32; o; o >>= 1) {
        t0 += __shfl_xor(t0, o);
        t1 += __shfl_xor(t1, o);
        t2 += __shfl_xor(t2, o);
        t3 += __shfl_xor(t3, o);
    }
    float4 av4;
    av4.x = e0 / t0;
    av4.y = e1 / t1;
    av4.z = e2 / t2;
    av4.w = e3 / t3;
    *reinterpret_cast<float4*>(&ash[wid][lane][0]) = av4;   // transposed attn stash

    // ---- PV: out[i,:] = sum_j attn[i,j]*h[j,:]; attn via uniform b128 broadcast ----
    const int dbase = 2 * lane;
    float o00 = 0.f, o01 = 0.f, o10 = 0.f, o11 = 0.f;
    float o20 = 0.f, o21 = 0.f, o30 = 0.f, o31 = 0.f;
    #pragma unroll 5
    for (int jj = 0; jj < kN; ++jj) {
        const float2 h2 = *reinterpret_cast<const float2*>(&hsh[jj * kRP + dbase]);
        const float4 aj = *reinterpret_cast<const float4*>(&ash[wid][jj][0]);  // uniform
        o00 += aj.x * h2.x;  o01 += aj.x * h2.y;
        o10 += aj.y * h2.x;  o11 += aj.y * h2.y;
        o20 += aj.z * h2.x;  o21 += aj.z * h2.y;
        o30 += aj.w * h2.x;  o31 += aj.w * h2.y;
    }
    if (i0 + 0 < kN) { float2 r{o00, o01}; *reinterpret_cast<float2*>(&outb[(i0 + 0) * kD + dbase]) = r; }
    if (i0 + 1 < kN) { float2 r{o10, o11}; *reinterpret_cast<float2*>(&outb[(i0 + 1) * kD + dbase]) = r; }
    if (i0 + 2 < kN) { float2 r{o20, o21}; *reinterpret_cast<float2*>(&outb[(i0 + 2) * kD + dbase]) = r; }
    if (i0 + 3 < kN) { float2 r{o30, o31}; *reinterpret_cast<float2*>(&outb[(i0 + 3) * kD + dbase]) = r; }
}

extern "C" void kernel_launch(void* const* d_in, const int* in_sizes, int n_in,
                              void* d_out, int out_size, void* d_ws, size_t ws_size,
                              hipStream_t stream) {
    const float* hidden = reinterpret_cast<const float*>(d_in[0]);
    const int*   adjp   = reinterpret_cast<const int*>(d_in[1]);
    const float* a0     = reinterpret_cast<const float*>(d_in[2]);
    const float* a1     = reinterpret_cast<const float*>(d_in[3]);
    const float* a2     = reinterpret_cast<const float*>(d_in[4]);
    const float* a3     = reinterpret_cast<const float*>(d_in[5]);
    float*       outp   = reinterpret_cast<float*>(d_out);

    gat_fused4_kernel<<<dim3(kB * 2), dim3(512), 0, stream>>>(
        hidden, adjp, a0, a1, a2, a3, outp);
}

// Round 5
// 20.060 us; speedup vs baseline: 5.9373x; 1.3923x over previous
//
#include <hip/hip_runtime.h>
#include <stdint.h>

typedef __attribute__((ext_vector_type(8))) short short8;
typedef __attribute__((ext_vector_type(4))) float f32x4;

namespace {
constexpr int   kN     = 50;
constexpr int   kD     = 128;
constexpr float kNeg   = -9.0e15f;
constexpr float kSlope = 0.2f;
constexpr int   HS32   = 132;   // f32 LDS row stride (H, a): conflict-free b128 pattern
constexpr int   HS16   = 136;   // bf16 LDS row stride (Hhi/Hlo): 16B-aligned rows, 2-way max
constexpr int   SS     = 68;    // score buffer stride (f32)
constexpr int   AS     = 52;    // transposed-attn stride (f32), 16B-aligned reads
}

union Pack8 { uint32_t u[4]; short8 s; };

__global__ __launch_bounds__(512)
void gat_mfma_kernel(const float* __restrict__ hidden,
                     const int*   __restrict__ adj,
                     const float* __restrict__ a0,
                     const float* __restrict__ a1,
                     const float* __restrict__ a2,
                     const float* __restrict__ a3,
                     float* __restrict__ out)
{
    __shared__ float          Hf [kN * HS32];   // 26.4 KB f32 H
    __shared__ unsigned short Hhi[kN * HS16];   // 13.6 KB bf16 hi(H)
    __shared__ unsigned short Hlo[kN * HS16];   // 13.6 KB bf16 lo(H)
    __shared__ float          Af [4 * HS32];    //  2.1 KB f32 relation vectors
    __shared__ float          Sa [kN * SS];     // 13.6 KB raw scores, K-half 0
    __shared__ float          Sb [kN * SS];     // 13.6 KB raw scores, K-half 1
    __shared__ float          At [64 * AS];     // 13.3 KB attn transposed [j][i]

    const int b    = blockIdx.x;
    const int tid  = threadIdx.x;
    const int lane = tid & 63;
    const int wid  = tid >> 6;

    const float* __restrict__ hb   = hidden + (size_t)b * (kN * kD);
    const int*   __restrict__ adjb = adj    + (size_t)b * (kN * kN);
    float*       __restrict__ outb = out    + (size_t)b * (kN * kD);

    // ---------------- phase 1: stage H (f32 + hi/lo bf16 split) and a_k ----------------
    const float4* hg = reinterpret_cast<const float4*>(hb);
    for (int idx = tid; idx < kN * (kD / 4); idx += 512) {
        const int j  = idx >> 5;
        const int d4 = idx & 31;
        const float4 v = hg[idx];
        *reinterpret_cast<float4*>(&Hf[j * HS32 + 4 * d4]) = v;

        const uint32_t u0 = __float_as_uint(v.x), u1 = __float_as_uint(v.y);
        const uint32_t u2 = __float_as_uint(v.z), u3 = __float_as_uint(v.w);
        const uint32_t h0 = u0 & 0xffff0000u, h1 = u1 & 0xffff0000u;
        const uint32_t h2 = u2 & 0xffff0000u, h3 = u3 & 0xffff0000u;
        uint2 hiw;
        hiw.x = h1 | (h0 >> 16);
        hiw.y = h3 | (h2 >> 16);
        const float r0 = v.x - __uint_as_float(h0);
        const float r1 = v.y - __uint_as_float(h1);
        const float r2 = v.z - __uint_as_float(h2);
        const float r3 = v.w - __uint_as_float(h3);
        uint2 low;
        low.x = (__float_as_uint(r1) & 0xffff0000u) | (__float_as_uint(r0) >> 16);
        low.y = (__float_as_uint(r3) & 0xffff0000u) | (__float_as_uint(r2) >> 16);
        *reinterpret_cast<uint2*>(&Hhi[j * HS16 + 4 * d4]) = hiw;
        *reinterpret_cast<uint2*>(&Hlo[j * HS16 + 4 * d4]) = low;
    }
    if (tid < 128) {
        const int k  = tid >> 5;
        const int d4 = tid & 31;
        const float* ap = (k == 0) ? a0 : (k == 1) ? a1 : (k == 2) ? a2 : a3;
        *reinterpret_cast<float4*>(&Af[k * HS32 + 4 * d4]) =
            *reinterpret_cast<const float4*>(ap + 4 * d4);
    }
    __syncthreads();

    // ---------------- phase 2: scores via MFMA (hi/lo split, split-K) ----------------
    // wave -> (i-tile, K-half). acc[jt][k] accumulates S_k partial for this K-half.
    {
        const int it = wid & 3;
        const int kh = wid >> 2;
        const int i0 = it * 16;
        const int g  = lane >> 4;
        const int f  = lane & 15;
        const int irow = (i0 + f < kN) ? (i0 + f) : (kN - 1);

        f32x4 acc[4][4];
        #pragma unroll
        for (int jt = 0; jt < 4; ++jt)
            #pragma unroll
            for (int k = 0; k < 4; ++k)
                acc[jt][k] = (f32x4){0.f, 0.f, 0.f, 0.f};

        #pragma unroll
        for (int ksl = 0; ksl < 2; ++ksl) {
            const int ks   = 2 * kh + ksl;
            const int dofs = 32 * ks + 8 * g;

            // A-side: h_i (8 f32) from Hf, per-lane row irow
            const float4 hA0 = *reinterpret_cast<const float4*>(&Hf[irow * HS32 + dofs]);
            const float4 hA1 = *reinterpret_cast<const float4*>(&Hf[irow * HS32 + dofs + 4]);
            float ha[8] = {hA0.x, hA0.y, hA0.z, hA0.w, hA1.x, hA1.y, hA1.z, hA1.w};

            // build q_k = h_i * a_k, split into hi/lo bf16 fragments
            short8 qhi[4], qlo[4];
            #pragma unroll
            for (int k = 0; k < 4; ++k) {
                const float4 av0 = *reinterpret_cast<const float4*>(&Af[k * HS32 + dofs]);
                const float4 av1 = *reinterpret_cast<const float4*>(&Af[k * HS32 + dofs + 4]);
                const float aa[8] = {av0.x, av0.y, av0.z, av0.w, av1.x, av1.y, av1.z, av1.w};
                Pack8 ph, pl;
                #pragma unroll
                for (int p = 0; p < 4; ++p) {
                    const float q0 = ha[2 * p]     * aa[2 * p];
                    const float q1 = ha[2 * p + 1] * aa[2 * p + 1];
                    const uint32_t b0 = __float_as_uint(q0) & 0xffff0000u;
                    const uint32_t b1 = __float_as_uint(q1) & 0xffff0000u;
                    ph.u[p] = b1 | (b0 >> 16);
                    const float s0 = q0 - __uint_as_float(b0);
                    const float s1 = q1 - __uint_as_float(b1);
                    pl.u[p] = (__float_as_uint(s1) & 0xffff0000u) | (__float_as_uint(s0) >> 16);
                }
                qhi[k] = ph.s;
                qlo[k] = pl.s;
            }

            // B-side: H rows j, hi/lo fragments; 3-term MFMA per relation
            #pragma unroll
            for (int jt = 0; jt < 4; ++jt) {
                const int jrow = (jt * 16 + f < kN) ? (jt * 16 + f) : (kN - 1);
                const short8 bh = *reinterpret_cast<const short8*>(&Hhi[jrow * HS16 + dofs]);
                const short8 bl = *reinterpret_cast<const short8*>(&Hlo[jrow * HS16 + dofs]);
                #pragma unroll
                for (int k = 0; k < 4; ++k) {
                    acc[jt][k] = __builtin_amdgcn_mfma_f32_16x16x32_bf16(qhi[k], bh, acc[jt][k], 0, 0, 0);
                    acc[jt][k] = __builtin_amdgcn_mfma_f32_16x16x32_bf16(qhi[k], bl, acc[jt][k], 0, 0, 0);
                    acc[jt][k] = __builtin_amdgcn_mfma_f32_16x16x32_bf16(qlo[k], bh, acc[jt][k], 0, 0, 0);
                }
            }
        }

        // select by adj (linear -> commutes with K-sum), write raw partials
        float* Sbuf = (kh == 0) ? Sa : Sb;
        #pragma unroll
        for (int jt = 0; jt < 4; ++jt) {
            const int j = jt * 16 + f;
            #pragma unroll
            for (int reg = 0; reg < 4; ++reg) {
                const int ii = i0 + 4 * g + reg;
                int adjv = 0;
                if (ii < kN && j < kN) adjv = adjb[ii * kN + j];
                const float val = (adjv == 1) ? acc[jt][0][reg]
                                : (adjv == 2) ? acc[jt][1][reg]
                                : (adjv == 3) ? acc[jt][2][reg]
                                : (adjv == 4) ? acc[jt][3][reg] : 0.f;
                if (ii < kN) Sbuf[ii * SS + j] = val;
            }
        }
    }
    __syncthreads();

    // ---------------- phase 3: softmax (wave per row), write transposed attn ----------------
    for (int r = wid; r < kN; r += 8) {
        const float x = Sa[r * SS + lane] + Sb[r * SS + lane];
        int adjv = 0;
        if (lane < kN) adjv = adjb[r * kN + lane];
        const bool valid = (adjv >= 1) && (adjv <= 4);
        const float lx = (x > 0.f) ? x : kSlope * x;
        float s = valid ? lx : kNeg;
        float m = s;
        #pragma unroll
        for (int o = 32; o; o >>= 1) m = fmaxf(m, __shfl_xor(m, o));
        const float e = (lane < kN) ? __expf(s - m) : 0.f;   // all-masked row -> uniform (matches ref)
        float t = e;
        #pragma unroll
        for (int o = 32; o; o >>= 1) t += __shfl_xor(t, o);
        At[lane * AS + r] = e / t;
    }
    __syncthreads();

    // ---------------- phase 4: PV in fp32 VALU: out[i,:] = sum_j attn[i,j] h[j,:] ----------------
    {
        const int it = wid & 3;
        const int dh = wid >> 2;
        const int i0 = it * 16;
        const int g  = lane >> 4;
        const int f  = lane & 15;
        const int db = 64 * dh + 4 * f;

        float4 o0 = {0.f, 0.f, 0.f, 0.f}, o1 = o0, o2 = o0, o3 = o0;
        #pragma unroll 5
        for (int j = 0; j < kN; ++j) {
            const float4 hv = *reinterpret_cast<const float4*>(&Hf[j * HS32 + db]);
            const float4 av = *reinterpret_cast<const float4*>(&At[j * AS + i0 + 4 * g]);
            o0.x += av.x * hv.x; o0.y += av.x * hv.y; o0.z += av.x * hv.z; o0.w += av.x * hv.w;
            o1.x += av.y * hv.x; o1.y += av.y * hv.y; o1.z += av.y * hv.z; o1.w += av.y * hv.w;
            o2.x += av.z * hv.x; o2.y += av.z * hv.y; o2.z += av.z * hv.z; o2.w += av.z * hv.w;
            o3.x += av.w * hv.x; o3.y += av.w * hv.y; o3.z += av.w * hv.z; o3.w += av.w * hv.w;
        }
        const int rbase = i0 + 4 * g;
        if (rbase + 0 < kN) *reinterpret_cast<float4*>(&outb[(rbase + 0) * kD + db]) = o0;
        if (rbase + 1 < kN) *reinterpret_cast<float4*>(&outb[(rbase + 1) * kD + db]) = o1;
        if (rbase + 2 < kN) *reinterpret_cast<float4*>(&outb[(rbase + 2) * kD + db]) = o2;
        if (rbase + 3 < kN) *reinterpret_cast<float4*>(&outb[(rbase + 3) * kD + db]) = o3;
    }
}

extern "C" void kernel_launch(void* const* d_in, const int* in_sizes, int n_in,
                              void* d_out, int out_size, void* d_ws, size_t ws_size,
                              hipStream_t stream) {
    const float* hidden = reinterpret_cast<const float*>(d_in[0]);
    const int*   adjp   = reinterpret_cast<const int*>(d_in[1]);
    const float* a0     = reinterpret_cast<const float*>(d_in[2]);
    const float* a1     = reinterpret_cast<const float*>(d_in[3]);
    const float* a2     = reinterpret_cast<const float*>(d_in[4]);
    const float* a3     = reinterpret_cast<const float*>(d_in[5]);
    float*       outp   = reinterpret_cast<float*>(d_out);

    gat_mfma_kernel<<<dim3(256), dim3(512), 0, stream>>>(
        hidden, adjp, a0, a1, a2, a3, outp);
}